// Round 12
// baseline (91.881 us; speedup 1.0000x reference)
//
#include <hip/hip_runtime.h>
#include <hip/hip_bf16.h>
#include <math.h>

#define SEQ 4096
#define HD  64
#define NBATCH 4

#define EM1   1.71828182845904523536f
#define INVD5 (1.0f/(4096.f + 5.f*EM1))
#define INVD4 (1.0f/(4096.f + 4.f*EM1))
#define INVD3 (1.0f/(4096.f + 3.f*EM1))

typedef __attribute__((ext_vector_type(8))) short short8;
typedef __attribute__((ext_vector_type(4))) float f32x4;

__device__ __forceinline__ f32x4 mfma16(short8 a, short8 b, f32x4 c) {
    return __builtin_amdgcn_mfma_f32_16x16x32_bf16(a, b, c, 0, 0, 0);
}

__device__ __forceinline__ short bfs(float x) {
    __hip_bfloat16 h = __float2bfloat16(x);
    return *(short*)&h;
}

__device__ __forceinline__ short8 pack8(float4 a, float4 b) {
    short8 r;
    r[0] = bfs(a.x); r[1] = bfs(a.y); r[2] = bfs(a.z); r[3] = bfs(a.w);
    r[4] = bfs(b.x); r[5] = bfs(b.y); r[6] = bfs(b.z); r[7] = bfs(b.w);
    return r;
}

__device__ __forceinline__ float blo(unsigned v) { return __uint_as_float(v << 16); }
__device__ __forceinline__ float bhi(unsigned v) { return __uint_as_float(v & 0xffff0000u); }
__device__ __forceinline__ float b2f(__hip_bfloat16 h) { return __bfloat162float(h); }

// ---------------------------------------------------------------------------
// Kernel 0: prepack W to bf16 (Wq scaled by exact 0.125) + zero Mfull.
// grid 19: blocks 0-2 pack, 3-18 zero 4 KB each of Mfull (ws is poisoned).
// ---------------------------------------------------------------------------
__global__ __launch_bounds__(256) void wpack_kernel(
    const float* __restrict__ Wq, const float* __restrict__ Wk,
    const float* __restrict__ Wv, __hip_bfloat16* __restrict__ Wb,
    float* __restrict__ Mfull)
{
    const int blk = blockIdx.x, tid = threadIdx.x;
    if (blk >= 3) {
        float4 z = make_float4(0.f, 0.f, 0.f, 0.f);
        *(float4*)&Mfull[(blk - 3) * 1024 + tid * 4] = z;
        return;
    }
    const float* W = (blk == 0) ? Wq : (blk == 1) ? Wk : Wv;
    const float s = (blk == 0) ? 0.125f : 1.f;
    const float* src = W + tid * 16;
    float4 a0 = *(const float4*)(src);
    float4 a1 = *(const float4*)(src + 4);
    float4 a2 = *(const float4*)(src + 8);
    float4 a3 = *(const float4*)(src + 12);
    a0.x*=s; a0.y*=s; a0.z*=s; a0.w*=s;
    a1.x*=s; a1.y*=s; a1.z*=s; a1.w*=s;
    a2.x*=s; a2.y*=s; a2.z*=s; a2.w*=s;
    a3.x*=s; a3.y*=s; a3.z*=s; a3.w*=s;
    __hip_bfloat16* dst = Wb + blk * 4096 + tid * 16;
    *(short8*)(dst)     = pack8(a0, a1);
    *(short8*)(dst + 8) = pack8(a2, a3);
}

// ---------------------------------------------------------------------------
// Kernel 1: projections via MFMA.  512 blocks x 128 thr (2 waves, 32 rows).
// ---------------------------------------------------------------------------
__global__ __launch_bounds__(128) void proj_kernel(
    const float* __restrict__ feat, const __hip_bfloat16* __restrict__ Wb,
    const float* __restrict__ bq, const float* __restrict__ bk,
    const float* __restrict__ bv,
    __hip_bfloat16* __restrict__ qsb, __hip_bfloat16* __restrict__ ktb,
    __hip_bfloat16* __restrict__ vtb,
    float* __restrict__ kpart, float* __restrict__ vpart)
{
    __shared__ __hip_bfloat16 tscr[64 * 72];   // [h][32 t] transposed tile
    __shared__ float kred[2][64];

    const int tid  = threadIdx.x;
    const int wave = tid >> 6, lane = tid & 63;
    const int quad = lane >> 4, ln = lane & 15;
    const int R0 = blockIdx.x * 32;            // [0, B*S)
    const int b  = R0 >> 12;
    const int t0 = R0 & (SEQ - 1);

    short8 af0, af1;
    {
        const float* fp = feat + (size_t)(R0 + wave * 16 + ln) * HD + quad * 8;
        af0 = pack8(*(const float4*)(fp),      *(const float4*)(fp + 4));
        af1 = pack8(*(const float4*)(fp + 32), *(const float4*)(fp + 36));
    }

    const float* Bs[3] = {bq, bk, bv};

    #pragma unroll
    for (int m = 0; m < 3; ++m) {
        const __hip_bfloat16* W = Wb + m * 4096;
        const float* bias = Bs[m];
        #pragma unroll
        for (int ct = 0; ct < 4; ++ct) {
            const int col = ct * 16 + ln;
            const __hip_bfloat16* wp = W + col * 64 + quad * 8;
            short8 b0 = *(const short8*)(wp);
            short8 b1 = *(const short8*)(wp + 32);
            f32x4 c = {};
            c = mfma16(af0, b0, c);
            c = mfma16(af1, b1, c);

            if (m == 0) {
                const float bl = bias[col] * 0.125f;
                #pragma unroll
                for (int r = 0; r < 4; ++r)
                    qsb[(size_t)(R0 + wave * 16 + quad * 4 + r) * HD + col] =
                        __float2bfloat16(c[r] + bl);
            } else {
                const float bl = bias[col];
                float tot = c[0] + c[1] + c[2] + c[3];
                tot += __shfl_xor(tot, 16);
                tot += __shfl_xor(tot, 32);
                if (quad == 0) kred[wave][col] = tot;
                #pragma unroll
                for (int r = 0; r < 4; ++r)
                    tscr[col * 72 + wave * 16 + quad * 4 + r] =
                        __float2bfloat16(c[r] + bl);
            }
        }
        if (m > 0) {
            __syncthreads();
            if (tid < 64)
                ((m == 1) ? kpart : vpart)[(size_t)blockIdx.x * 64 + tid] =
                    kred[0][tid] + kred[1][tid] + 32.f * bias[tid];
            __hip_bfloat16* dst = (m == 1) ? ktb : vtb;
            #pragma unroll
            for (int i = 0; i < 2; ++i) {
                const int tsk = i * 128 + tid;     // 256 tasks: 64 h x 4 chunks
                const int hh = tsk >> 2, c8 = tsk & 3;
                short8 vv = *(const short8*)&tscr[hh * 72 + c8 * 8];
                *(short8*)(dst + ((size_t)(b * HD + hh)) * SEQ + t0 + c8 * 8) = vv;
            }
            __syncthreads();
        }
    }
}

// ---------------------------------------------------------------------------
// Kernel 2: Mfull[h1][h2] += sum_t k[t][h1]*locv5[t][h2] per 32-t chunk via
// MFMA + spread fp32 atomics (2M atomics / 4096 lines = ~32 line-ops each).
// grid (128, 5): y<4 = batch, y==4/x<16 = correction slabs (mktotF, Vtot,
// Mcorr; slab 2 unused).
// ---------------------------------------------------------------------------
__global__ __launch_bounds__(256) void mkernel(
    const __hip_bfloat16* __restrict__ ktb, const __hip_bfloat16* __restrict__ vtb,
    const float* __restrict__ kpart, const float* __restrict__ vpart,
    float* __restrict__ Mfull, float* __restrict__ Mcorr,
    float* __restrict__ mktotF, float* __restrict__ Vtot)
{
    __shared__ float vws[64 * 38];              // v window [h][t0-2..t0+34)
    __shared__ __hip_bfloat16 lvt[64 * 40];     // locv5^T [h][32 t]
    __shared__ float scr[4][64];
    __shared__ float ktl[64], vtl[64];
    __shared__ float lc[4][64], vv_e[4][64];

    const int tid = threadIdx.x;

    if (blockIdx.y == 4) {
        if (blockIdx.x >= 16) return;
        const int b = blockIdx.x >> 2, slab = blockIdx.x & 3;
        if (slab == 2) return;
        const int h = tid & 63, g = tid >> 6;

        if (slab == 0 || slab == 3) {
            float kp = 0.f;
            for (int j = 0; j < 32; ++j)
                kp += kpart[(size_t)(b * 128 + g * 32 + j) * 64 + h];
            scr[g][h] = kp;
            __syncthreads();
            if (tid < 64) ktl[tid] = scr[0][tid] + scr[1][tid] + scr[2][tid] + scr[3][tid];
        }
        if (slab == 0) {
            __syncthreads();
            if (tid < 64) {
                const int hh = tid;
                const float kt = ktl[hh];
                const __hip_bfloat16* kr = ktb + (size_t)(b * 64 + hh) * SEQ;
                const float e0 = b2f(kr[0]), e1 = b2f(kr[1]), e2 = b2f(kr[2]), e3 = b2f(kr[3]);
                const float f0 = b2f(kr[SEQ-4]), f1 = b2f(kr[SEQ-3]);
                const float f2 = b2f(kr[SEQ-2]), f3 = b2f(kr[SEQ-1]);
                const float Sint = 5.f*kt - 4.f*e0 - 3.f*e1 - 2.f*e2 - e3
                                 - f0 - 2.f*f1 - 3.f*f2 - 4.f*f3;
                const float SlocD = Sint * INVD5
                                  + (e0+e1+e2 + f1+f2+f3) * INVD3
                                  + (e0+e1+e2+e3 + f0+f1+f2+f3) * INVD4;
                mktotF[b * 64 + hh] =
                    kt * (4092.f*INVD5 + 2.f*INVD4 + 2.f*INVD3) + EM1 * SlocD;
            }
        } else if (slab == 1) {
            float vp = 0.f;
            for (int j = 0; j < 32; ++j)
                vp += vpart[(size_t)(b * 128 + g * 32 + j) * 64 + h];
            scr[g][h] = vp;
            __syncthreads();
            if (tid < 64)
                Vtot[b * 64 + tid] = scr[0][tid] + scr[1][tid] + scr[2][tid] + scr[3][tid];
        } else {
            __syncthreads();      // ktl ready
            {
                float vp = 0.f;
                for (int j = 0; j < 32; ++j)
                    vp += vpart[(size_t)(b * 128 + g * 32 + j) * 64 + h];
                scr[g][h] = vp;
            }
            __syncthreads();
            if (tid < 64) vtl[tid] = scr[0][tid] + scr[1][tid] + scr[2][tid] + scr[3][tid];
            if (tid < 64) {
                const int hh = tid;
                const __hip_bfloat16* kr = ktb + (size_t)(b * 64 + hh) * SEQ;
                const float e0 = b2f(kr[0]), e1 = b2f(kr[1]), e2 = b2f(kr[2]), e3 = b2f(kr[3]);
                const float f0 = b2f(kr[SEQ-4]), f1 = b2f(kr[SEQ-3]);
                const float f2 = b2f(kr[SEQ-2]), f3 = b2f(kr[SEQ-1]);
                lc[0][hh] = e0 + e1 + e2;
                lc[1][hh] = e0 + e1 + e2 + e3;
                lc[2][hh] = f0 + f1 + f2 + f3;
                lc[3][hh] = f1 + f2 + f3;
                const __hip_bfloat16* vr = vtb + (size_t)(b * 64 + hh) * SEQ;
                vv_e[0][hh] = b2f(vr[0]);
                vv_e[1][hh] = b2f(vr[1]);
                vv_e[2][hh] = b2f(vr[SEQ-2]);
                vv_e[3][hh] = b2f(vr[SEQ-1]);
            }
            __syncthreads();
            const float dd3 = INVD3 - INVD5, dd4 = INVD4 - INVD5;
            const int h1 = tid >> 2;
            const float l0 = lc[0][h1], l1 = lc[1][h1], l2 = lc[2][h1], l3 = lc[3][h1];
            const float kt1 = ktl[h1];
            #pragma unroll
            for (int j = 0; j < 16; ++j) {
                const int h2 = (tid & 3) * 16 + j;
                const float VD = INVD5 * vtl[h2]
                               + dd3 * (vv_e[0][h2] + vv_e[3][h2])
                               + dd4 * (vv_e[1][h2] + vv_e[2][h2]);
                Mcorr[(size_t)(b * 64 + h1) * 64 + h2] =
                    EM1 * (dd3 * (l0 * vv_e[0][h2] + l3 * vv_e[3][h2])
                         + dd4 * (l1 * vv_e[1][h2] + l2 * vv_e[2][h2]))
                    + kt1 * VD;
            }
        }
        return;
    }

    // ---------------- main GEMM chunk ----------------
    const int b = blockIdx.y, chunk = blockIdx.x;
    const int t0 = chunk * 32;

    for (int i = tid; i < 64 * 18; i += 256) {
        const int r = i / 18, c = i - r * 18;
        const int gt = t0 - 2 + c * 2;
        unsigned val = 0;
        if (gt >= 0 && gt <= SEQ - 2)
            val = *(const unsigned*)(vtb + (size_t)(b * 64 + r) * SEQ + gt);
        vws[r * 38 + c * 2]     = blo(val);
        vws[r * 38 + c * 2 + 1] = bhi(val);
    }
    __syncthreads();

    {
        const int h = tid & 63, g = tid >> 6;
        float w[12];
        #pragma unroll
        for (int j = 0; j < 12; ++j) w[j] = vws[h * 38 + g * 8 + j];
        short8 o;
        #pragma unroll
        for (int i = 0; i < 8; ++i)
            o[i] = bfs(w[i] + w[i+1] + w[i+2] + w[i+3] + w[i+4]);
        *(short8*)&lvt[h * 40 + g * 8] = o;
    }
    __syncthreads();

    const int wave = tid >> 6, lane = tid & 63, quad = lane >> 4, ln = lane & 15;
    short8 a = *(const short8*)(ktb + (size_t)(b * 64 + wave * 16 + ln) * SEQ
                                + t0 + quad * 8);
    f32x4 acc[4] = {};
    #pragma unroll
    for (int ct = 0; ct < 4; ++ct) {
        short8 bb = *(const short8*)&lvt[(ct * 16 + ln) * 40 + quad * 8];
        acc[ct] = mfma16(a, bb, acc[ct]);
    }
    float* mf = Mfull + b * 4096;
    #pragma unroll
    for (int ct = 0; ct < 4; ++ct)
        #pragma unroll
        for (int r = 0; r < 4; ++r)
            atomicAdd(&mf[(wave * 16 + quad * 4 + r) * 64 + ct * 16 + ln],
                      acc[ct][r]);
}

// ---------------------------------------------------------------------------
// Kernel 3: out = (Vtot + qs*M) / (4096 + qs*mktot).  256 blocks x 256 thr
// (4 waves, 64 rows).  MT bf16 built in LDS from Mfull/Mcorr (L2-hot 80 KB);
// denominator via lane-uniform mktot B-fragment (no shuffle).
// ---------------------------------------------------------------------------
__global__ __launch_bounds__(256) void out_kernel(
    const __hip_bfloat16* __restrict__ qsb, const float* __restrict__ Mfull,
    const float* __restrict__ Mcorr, const float* __restrict__ mktotF,
    const float* __restrict__ Vtot, float* __restrict__ out)
{
    __shared__ __hip_bfloat16 tscr[64 * 72];   // MT [h2][h1]

    const int tid  = threadIdx.x;
    const int wave = tid >> 6, lane = tid & 63;
    const int quad = lane >> 4, ln = lane & 15;
    const int R0 = blockIdx.x * 64;
    const int b  = R0 >> 12;

    {
        const int h2 = tid & 63, seg = tid >> 6;
        #pragma unroll
        for (int j = 0; j < 16; ++j) {
            const int h1 = seg * 16 + j;
            const float m = (EM1 * INVD5) * Mfull[b * 4096 + h1 * 64 + h2]
                          + Mcorr[(size_t)(b * 64 + h1) * 64 + h2];
            tscr[h2 * 72 + h1] = __float2bfloat16(m);
        }
    }
    __syncthreads();

    short8 qa0, qa1;
    {
        const __hip_bfloat16* qp = qsb + (size_t)(R0 + wave * 16 + ln) * HD + quad * 8;
        qa0 = *(const short8*)qp;
        qa1 = *(const short8*)(qp + 32);
    }
    short8 mk0, mk1;
    #pragma unroll
    for (int j = 0; j < 8; ++j) {
        mk0[j] = bfs(mktotF[b * 64 + quad * 8 + j]);
        mk1[j] = bfs(mktotF[b * 64 + 32 + quad * 8 + j]);
    }

    f32x4 acc[4];
    #pragma unroll
    for (int ct = 0; ct < 4; ++ct) {
        short8 b0 = *(const short8*)&tscr[(ct * 16 + ln) * 72 + quad * 8];
        short8 b1 = *(const short8*)&tscr[(ct * 16 + ln) * 72 + 32 + quad * 8];
        f32x4 c = {};
        c = mfma16(qa0, b0, c);
        c = mfma16(qa1, b1, c);
        acc[ct] = c;
    }
    f32x4 accd = {};
    accd = mfma16(qa0, mk0, accd);
    accd = mfma16(qa1, mk1, accd);     // lane-uniform: den per row

    float vt[4];
    #pragma unroll
    for (int ct = 0; ct < 4; ++ct) vt[ct] = Vtot[b * 64 + ct * 16 + ln];

    float inv[4];
    #pragma unroll
    for (int r = 0; r < 4; ++r) inv[r] = 1.f / (4096.f + accd[r]);

    #pragma unroll
    for (int ct = 0; ct < 4; ++ct)
        #pragma unroll
        for (int r = 0; r < 4; ++r)
            out[(size_t)(R0 + wave * 16 + quad * 4 + r) * HD + ct * 16 + ln] =
                (vt[ct] + acc[ct][r]) * inv[r];
}

// ---------------------------------------------------------------------------
extern "C" void kernel_launch(void* const* d_in, const int* in_sizes, int n_in,
                              void* d_out, int out_size, void* d_ws, size_t ws_size,
                              hipStream_t stream)
{
    const float* feat = (const float*)d_in[0];
    const float* Wq = (const float*)d_in[1];
    const float* bq = (const float*)d_in[2];
    const float* Wk = (const float*)d_in[3];
    const float* bk = (const float*)d_in[4];
    const float* Wv = (const float*)d_in[5];
    const float* bv = (const float*)d_in[6];
    float* out = (float*)d_out;

    char* ws = (char*)d_ws;
    __hip_bfloat16* qsb    = (__hip_bfloat16*)(ws + 0);                  // 2 MB
    __hip_bfloat16* ktb    = (__hip_bfloat16*)(ws + (2u << 20));         // 2 MB
    __hip_bfloat16* vtb    = (__hip_bfloat16*)(ws + (4u << 20));         // 2 MB
    float*          kpart  = (float*)(ws + (6u << 20));                  // 128 KB
    float*          vpart  = (float*)(ws + (6u << 20) + 131072);         // 128 KB
    float*          Mfull  = (float*)(ws + (6u << 20) + 262144);         // 64 KB
    float*          Mcorr  = (float*)(ws + (6u << 20) + 327680);         // 64 KB
    float*          mktotF = (float*)(ws + (6u << 20) + 393216);         // 1 KB
    float*          Vtot   = (float*)(ws + (6u << 20) + 394240);         // 1 KB
    __hip_bfloat16* Wb     = (__hip_bfloat16*)(ws + (6u << 20) + 395264);// 24 KB

    wpack_kernel<<<dim3(19), dim3(256), 0, stream>>>(Wq, Wk, Wv, Wb, Mfull);
    proj_kernel<<<dim3(512), dim3(128), 0, stream>>>(
        feat, Wb, bq, bk, bv, qsb, ktb, vtb, kpart, vpart);
    mkernel<<<dim3(128, 5), dim3(256), 0, stream>>>(
        ktb, vtb, kpart, vpart, Mfull, Mcorr, mktotF, Vtot);
    out_kernel<<<dim3(256), dim3(256), 0, stream>>>(
        qsb, Mfull, Mcorr, mktotF, Vtot, out);
}

// Round 13
// 83.409 us; speedup vs baseline: 1.1016x; 1.1016x over previous
//
#include <hip/hip_runtime.h>
#include <hip/hip_bf16.h>
#include <math.h>

#define SEQ 4096
#define HD  64
#define NBATCH 4

#define EM1   1.71828182845904523536f
#define INVD5 (1.0f/(4096.f + 5.f*EM1))
#define INVD4 (1.0f/(4096.f + 4.f*EM1))
#define INVD3 (1.0f/(4096.f + 3.f*EM1))

typedef __attribute__((ext_vector_type(8))) short short8;
typedef __attribute__((ext_vector_type(4))) float f32x4;

__device__ __forceinline__ f32x4 mfma16(short8 a, short8 b, f32x4 c) {
    return __builtin_amdgcn_mfma_f32_16x16x32_bf16(a, b, c, 0, 0, 0);
}

__device__ __forceinline__ short bfs(float x) {
    __hip_bfloat16 h = __float2bfloat16(x);
    return *(short*)&h;
}

__device__ __forceinline__ short8 pack8(float4 a, float4 b) {
    short8 r;
    r[0] = bfs(a.x); r[1] = bfs(a.y); r[2] = bfs(a.z); r[3] = bfs(a.w);
    r[4] = bfs(b.x); r[5] = bfs(b.y); r[6] = bfs(b.z); r[7] = bfs(b.w);
    return r;
}

__device__ __forceinline__ float b2f(__hip_bfloat16 h) { return __bfloat162float(h); }

// ---------------------------------------------------------------------------
// Kernel 0: prepack W to bf16 (Wq scaled by exact 0.125).  3 blocks.
// ---------------------------------------------------------------------------
__global__ __launch_bounds__(256) void wpack_kernel(
    const float* __restrict__ Wq, const float* __restrict__ Wk,
    const float* __restrict__ Wv, __hip_bfloat16* __restrict__ Wb)
{
    const int blk = blockIdx.x, tid = threadIdx.x;
    const float* W = (blk == 0) ? Wq : (blk == 1) ? Wk : Wv;
    const float s = (blk == 0) ? 0.125f : 1.f;
    const float* src = W + tid * 16;
    float4 a0 = *(const float4*)(src);
    float4 a1 = *(const float4*)(src + 4);
    float4 a2 = *(const float4*)(src + 8);
    float4 a3 = *(const float4*)(src + 12);
    a0.x*=s; a0.y*=s; a0.z*=s; a0.w*=s;
    a1.x*=s; a1.y*=s; a1.z*=s; a1.w*=s;
    a2.x*=s; a2.y*=s; a2.z*=s; a2.w*=s;
    a3.x*=s; a3.y*=s; a3.z*=s; a3.w*=s;
    __hip_bfloat16* dst = Wb + blk * 4096 + tid * 16;
    *(short8*)(dst)     = pack8(a0, a1);
    *(short8*)(dst + 8) = pack8(a2, a3);
}

// ---------------------------------------------------------------------------
// Kernel 1: fused projection + M-chunk GEMM.  512 blocks x 128 thr (2 waves,
// 32 rows = one 32-t chunk of one batch).
//  - q -> qsb (bf16, prescaled)
//  - k,v -> transposed LDS tiles only (no global round trip)
//  - v halo rows (t0-2,t0-1,t0+32,t0+33) recomputed via MFMA (A lanes 0,1)
//  - locv5^T built in LDS, then 8 MFMAs: Mpart[chunk] = k^T · locv5
//  - kpart/vpart column sums; blocks at chunk 0/127 export 8 edge k-rows
// ---------------------------------------------------------------------------
__global__ __launch_bounds__(128) void projm_kernel(
    const float* __restrict__ feat, const __hip_bfloat16* __restrict__ Wb,
    const float* __restrict__ bq, const float* __restrict__ bk,
    const float* __restrict__ bv,
    __hip_bfloat16* __restrict__ qsb, float* __restrict__ kpart,
    float* __restrict__ vpart, __hip_bfloat16* __restrict__ Mpart,
    float* __restrict__ kedge)
{
    __shared__ __hip_bfloat16 kT[64 * 40];    // [h][t-local 0..31]
    __shared__ __hip_bfloat16 vT[64 * 40];    // [h][idx 0..35] = t0-2 .. t0+33
    __shared__ __hip_bfloat16 lvt[64 * 40];   // locv5^T [h][t-local 0..31]
    __shared__ float kred[2][64];
    __shared__ float vred[2][64];

    const int tid  = threadIdx.x;
    const int wave = tid >> 6, lane = tid & 63;
    const int quad = lane >> 4, ln = lane & 15;
    const int R0 = blockIdx.x * 32;            // [0, B*S)
    const int b  = R0 >> 12;
    const int t0 = R0 & (SEQ - 1);
    const int chunk = blockIdx.x & 127;

    // main A-fragments (32 rows)
    short8 af0, af1;
    {
        const float* fp = feat + (size_t)(R0 + wave * 16 + ln) * HD + quad * 8;
        af0 = pack8(*(const float4*)(fp),      *(const float4*)(fp + 4));
        af1 = pack8(*(const float4*)(fp + 32), *(const float4*)(fp + 36));
    }

    // halo A-fragments: wave0 -> rows t0-2,t0-1 (lanes ln=0,1); wave1 -> t0+32,t0+33
    short8 hf0, hf1;
    const bool hflag = (wave == 0) ? (t0 > 0) : (t0 < SEQ - 32);
    {
        const int hrow = (wave == 0) ? (t0 - 2 + ln) : (t0 + 32 + ln);
        if (ln < 2 && hflag) {
            const float* fp = feat + ((size_t)(b << 12) + hrow) * HD + quad * 8;
            hf0 = pack8(*(const float4*)(fp),      *(const float4*)(fp + 4));
            hf1 = pack8(*(const float4*)(fp + 32), *(const float4*)(fp + 36));
        } else {
            #pragma unroll
            for (int j = 0; j < 8; ++j) { hf0[j] = 0; hf1[j] = 0; }
        }
    }

    const float* Bs[3] = {bq, bk, bv};

    #pragma unroll
    for (int m = 0; m < 3; ++m) {
        const __hip_bfloat16* W = Wb + m * 4096;
        const float* bias = Bs[m];
        #pragma unroll
        for (int ct = 0; ct < 4; ++ct) {
            const int col = ct * 16 + ln;
            const __hip_bfloat16* wp = W + col * 64 + quad * 8;
            short8 b0 = *(const short8*)(wp);
            short8 b1 = *(const short8*)(wp + 32);
            f32x4 c = {};
            c = mfma16(af0, b0, c);
            c = mfma16(af1, b1, c);

            if (m == 0) {
                const float bl = bias[col] * 0.125f;
                #pragma unroll
                for (int r = 0; r < 4; ++r)
                    qsb[(size_t)(R0 + wave * 16 + quad * 4 + r) * HD + col] =
                        __float2bfloat16(c[r] + bl);
            } else if (m == 1) {
                const float bl = bias[col];
                float tot = c[0] + c[1] + c[2] + c[3];
                tot += __shfl_xor(tot, 16);
                tot += __shfl_xor(tot, 32);
                if (quad == 0) kred[wave][col] = tot;
                #pragma unroll
                for (int r = 0; r < 4; ++r)
                    kT[col * 40 + wave * 16 + quad * 4 + r] =
                        __float2bfloat16(c[r] + bl);
            } else {
                const float bl = bias[col];
                float tot = c[0] + c[1] + c[2] + c[3];
                tot += __shfl_xor(tot, 16);
                tot += __shfl_xor(tot, 32);
                if (quad == 0) vred[wave][col] = tot;
                #pragma unroll
                for (int r = 0; r < 4; ++r)
                    vT[col * 40 + 2 + wave * 16 + quad * 4 + r] =
                        __float2bfloat16(c[r] + bl);
                // halo rows for this ct (reuse b0/b1): C rows 0,1 = halo
                f32x4 hc = {};
                hc = mfma16(hf0, b0, hc);
                hc = mfma16(hf1, b1, hc);
                if (quad == 0) {
                    const int base = (wave == 0) ? 0 : 34;
                    vT[col * 40 + base]     = __float2bfloat16(hflag ? hc[0] + bl : 0.f);
                    vT[col * 40 + base + 1] = __float2bfloat16(hflag ? hc[1] + bl : 0.f);
                }
            }
        }
    }
    __syncthreads();

    // column-sum partials (128 per batch)
    if (tid < 64) {
        kpart[(size_t)blockIdx.x * 64 + tid] =
            kred[0][tid] + kred[1][tid] + 32.f * bk[tid];
        vpart[(size_t)blockIdx.x * 64 + tid] =
            vred[0][tid] + vred[1][tid] + 32.f * bv[tid];
    }

    // locv5^T: thread (h, wave) -> 16 t's; window idx tl..tl+4 == t-2..t+2
    {
        const int h = tid & 63;
        const int tb = wave * 16;
        float w[21];
        #pragma unroll
        for (int j = 0; j < 21; ++j) w[j] = b2f(vT[h * 40 + tb + j]);
        #pragma unroll
        for (int i = 0; i < 16; ++i)
            lvt[h * 40 + tb + i] =
                __float2bfloat16(w[i] + w[i+1] + w[i+2] + w[i+3] + w[i+4]);
    }

    // export edge k rows for mktot closed form
    if (chunk == 0) {
        #pragma unroll
        for (int i = 0; i < 2; ++i) {
            const int idx = i * 128 + tid;
            const int t = idx >> 6, h = idx & 63;
            kedge[b * 512 + t * 64 + h] = b2f(kT[h * 40 + t]);
        }
    } else if (chunk == 127) {
        #pragma unroll
        for (int i = 0; i < 2; ++i) {
            const int idx = i * 128 + tid;
            const int t = idx >> 6, h = idx & 63;
            kedge[b * 512 + (4 + t) * 64 + h] = b2f(kT[h * 40 + 28 + t]);
        }
    }
    __syncthreads();

    // GEMM: M_chunk[h1][h2] = sum_t k[t][h1]*locv5[t][h2], K=32, 8 MFMAs/wave
    __hip_bfloat16* mp = Mpart + (size_t)(b * 128 + chunk) * 4096;
    #pragma unroll
    for (int p = 0; p < 2; ++p) {
        const int strip = wave * 2 + p;
        short8 a = *(const short8*)&kT[(strip * 16 + ln) * 40 + quad * 8];
        #pragma unroll
        for (int ct = 0; ct < 4; ++ct) {
            short8 bb = *(const short8*)&lvt[(ct * 16 + ln) * 40 + quad * 8];
            f32x4 acc = {};
            acc = mfma16(a, bb, acc);
            #pragma unroll
            for (int r = 0; r < 4; ++r)
                mp[(strip * 16 + quad * 4 + r) * 64 + ct * 16 + ln] =
                    __float2bfloat16(acc[r]);
        }
    }
}

// ---------------------------------------------------------------------------
// Kernel 2: grid (65, B).  x<64: MTm[h2][h1] = bf16(EM1*INVD5 * sum_c Mpart).
// x==64: prep — ktot/Vtot from partials, mktot closed form (kedge), VDs.
// ---------------------------------------------------------------------------
__global__ __launch_bounds__(256) void redprep_kernel(
    const __hip_bfloat16* __restrict__ Mpart, const float* __restrict__ kpart,
    const float* __restrict__ vpart, const float* __restrict__ kedge,
    __hip_bfloat16* __restrict__ MTm, float* __restrict__ mktotF,
    float* __restrict__ ktotF, float* __restrict__ VDs,
    float* __restrict__ VtotF)
{
    __shared__ float red[4][64];
    __shared__ float red2[4][64];
    const int b = blockIdx.y, x = blockIdx.x;
    const int tid = threadIdx.x;
    const int g = tid >> 6, h2 = tid & 63;

    if (x < 64) {
        const int h1 = x;
        float s = 0.f;
        for (int c = g * 32; c < g * 32 + 32; ++c)
            s += b2f(Mpart[(size_t)(b * 128 + c) * 4096 + h1 * 64 + h2]);
        red[g][h2] = s;
        __syncthreads();
        if (tid < 64)
            MTm[(size_t)b * 4096 + tid * 64 + h1] = __float2bfloat16(
                (EM1 * INVD5) * (red[0][tid] + red[1][tid] + red[2][tid] + red[3][tid]));
        return;
    }

    // prep
    {
        float kp = 0.f, vp = 0.f;
        for (int j = 0; j < 32; ++j) {
            kp += kpart[(size_t)(b * 128 + g * 32 + j) * 64 + h2];
            vp += vpart[(size_t)(b * 128 + g * 32 + j) * 64 + h2];
        }
        red[g][h2] = kp;
        red2[g][h2] = vp;
    }
    __syncthreads();
    if (tid < 64) {
        const int hh = tid;
        const float kt = red[0][hh] + red[1][hh] + red[2][hh] + red[3][hh];
        const float vt = red2[0][hh] + red2[1][hh] + red2[2][hh] + red2[3][hh];
        const float e0 = kedge[b * 512 + 0 * 64 + hh];
        const float e1 = kedge[b * 512 + 1 * 64 + hh];
        const float e2 = kedge[b * 512 + 2 * 64 + hh];
        const float e3 = kedge[b * 512 + 3 * 64 + hh];
        const float f0 = kedge[b * 512 + 4 * 64 + hh];
        const float f1 = kedge[b * 512 + 5 * 64 + hh];
        const float f2 = kedge[b * 512 + 6 * 64 + hh];
        const float f3 = kedge[b * 512 + 7 * 64 + hh];
        const float Sint = 5.f*kt - 4.f*e0 - 3.f*e1 - 2.f*e2 - e3
                         - f0 - 2.f*f1 - 3.f*f2 - 4.f*f3;
        const float SlocD = Sint * INVD5
                          + (e0+e1+e2 + f1+f2+f3) * INVD3
                          + (e0+e1+e2+e3 + f0+f1+f2+f3) * INVD4;
        mktotF[b * 64 + hh] = kt * (4092.f*INVD5 + 2.f*INVD4 + 2.f*INVD3) + EM1 * SlocD;
        ktotF[b * 64 + hh]  = kt;
        VDs[b * 64 + hh]    = INVD5 * vt;
        VtotF[b * 64 + hh]  = vt;
    }
}

// ---------------------------------------------------------------------------
// Kernel 3: out = (Vtot + qs·Mmain + (qs·ktot)·VDs) / (4096 + qs·mktot).
// grid 1024 x 64.  12 MFMAs; denominators & ktot-dot via uniform-B trick.
// ---------------------------------------------------------------------------
__global__ __launch_bounds__(64) void out_kernel(
    const __hip_bfloat16* __restrict__ qsb, const __hip_bfloat16* __restrict__ MTm,
    const float* __restrict__ mktotF, const float* __restrict__ ktotF,
    const float* __restrict__ VDs, const float* __restrict__ VtotF,
    float* __restrict__ out)
{
    const int tid = threadIdx.x;
    const int quad = tid >> 4, ln = tid & 15;
    const int R0 = blockIdx.x * 16;
    const int b = R0 >> 12;

    short8 qa0, qa1;
    {
        const __hip_bfloat16* qp = qsb + (size_t)(R0 + ln) * HD + quad * 8;
        qa0 = *(const short8*)qp;
        qa1 = *(const short8*)(qp + 32);
    }

    const __hip_bfloat16* mtb = MTm + (size_t)b * 4096;
    f32x4 acc[4];
    #pragma unroll
    for (int ct = 0; ct < 4; ++ct) {
        short8 b0 = *(const short8*)(mtb + (ct * 16 + ln) * 64 + quad * 8);
        short8 b1 = *(const short8*)(mtb + (ct * 16 + ln) * 64 + 32 + quad * 8);
        f32x4 c = {};
        c = mfma16(qa0, b0, c);
        c = mfma16(qa1, b1, c);
        acc[ct] = c;
    }

    // uniform-B fragments: every lane holds the same vector slice
    short8 mk0, mk1, kt0, kt1;
    #pragma unroll
    for (int j = 0; j < 8; ++j) {
        mk0[j] = bfs(mktotF[b * 64 + quad * 8 + j]);
        mk1[j] = bfs(mktotF[b * 64 + 32 + quad * 8 + j]);
        kt0[j] = bfs(ktotF[b * 64 + quad * 8 + j]);
        kt1[j] = bfs(ktotF[b * 64 + 32 + quad * 8 + j]);
    }
    f32x4 accd = {}, acck = {};
    accd = mfma16(qa0, mk0, accd);
    accd = mfma16(qa1, mk1, accd);     // den per row (lane-uniform)
    acck = mfma16(qa0, kt0, acck);
    acck = mfma16(qa1, kt1, acck);     // qs·ktot per row

    float vt[4], vd[4];
    #pragma unroll
    for (int ct = 0; ct < 4; ++ct) {
        vt[ct] = VtotF[b * 64 + ct * 16 + ln];
        vd[ct] = VDs[b * 64 + ct * 16 + ln];
    }

    float inv[4];
    #pragma unroll
    for (int r = 0; r < 4; ++r) inv[r] = 1.f / (4096.f + accd[r]);

    #pragma unroll
    for (int ct = 0; ct < 4; ++ct)
        #pragma unroll
        for (int r = 0; r < 4; ++r)
            out[(size_t)(R0 + quad * 4 + r) * HD + ct * 16 + ln] =
                (vt[ct] + acc[ct][r] + acck[r] * vd[ct]) * inv[r];
}

// ---------------------------------------------------------------------------
extern "C" void kernel_launch(void* const* d_in, const int* in_sizes, int n_in,
                              void* d_out, int out_size, void* d_ws, size_t ws_size,
                              hipStream_t stream)
{
    const float* feat = (const float*)d_in[0];
    const float* Wq = (const float*)d_in[1];
    const float* bq = (const float*)d_in[2];
    const float* Wk = (const float*)d_in[3];
    const float* bk = (const float*)d_in[4];
    const float* Wv = (const float*)d_in[5];
    const float* bv = (const float*)d_in[6];
    float* out = (float*)d_out;

    char* ws = (char*)d_ws;
    __hip_bfloat16* qsb    = (__hip_bfloat16*)(ws + 0);                  // 2 MB
    __hip_bfloat16* Mpart  = (__hip_bfloat16*)(ws + (2u << 20));         // 4 MB
    float*          kpart  = (float*)(ws + (6u << 20));                  // 128 KB
    float*          vpart  = (float*)(ws + (6u << 20) + 131072);         // 128 KB
    float*          kedge  = (float*)(ws + (6u << 20) + 262144);         // 8 KB
    __hip_bfloat16* MTm    = (__hip_bfloat16*)(ws + (6u << 20) + 270336);// 32 KB
    float*          mktotF = (float*)(ws + (6u << 20) + 303104);         // 1 KB
    float*          ktotF  = (float*)(ws + (6u << 20) + 304128);         // 1 KB
    float*          VDs    = (float*)(ws + (6u << 20) + 305152);         // 1 KB
    float*          VtotF  = (float*)(ws + (6u << 20) + 306176);         // 1 KB
    __hip_bfloat16* Wb     = (__hip_bfloat16*)(ws + (6u << 20) + 307200);// 24 KB

    wpack_kernel<<<dim3(3), dim3(256), 0, stream>>>(Wq, Wk, Wv, Wb);
    projm_kernel<<<dim3(512), dim3(128), 0, stream>>>(
        feat, Wb, bq, bk, bv, qsb, kpart, vpart, Mpart, kedge);
    redprep_kernel<<<dim3(65, NBATCH), dim3(256), 0, stream>>>(
        Mpart, kpart, vpart, kedge, MTm, mktotF, ktotF, VDs, VtotF);
    out_kernel<<<dim3(1024), dim3(64), 0, stream>>>(
        qsb, MTm, mktotF, ktotF, VDs, VtotF, out);
}